// Round 1
// baseline (66.477 us; speedup 1.0000x reference)
//
#include <hip/hip_runtime.h>
#include <hip/hip_bf16.h>

#define PAD 15
#define NTAGS 15
#define SEQ_T 512
#define SPB 8                      // sequences per block (4 fwd-wave groups + 4 bwd)
#define LOG2E 1.4426950408889634f
#define LN2   0.6931471805599453f

__device__ __forceinline__ float max15(const float* A) {
  float m0 = fmaxf(fmaxf(A[0], A[1]), A[2]);
  float m1 = fmaxf(fmaxf(A[3], A[4]), A[5]);
  float m2 = fmaxf(fmaxf(A[6], A[7]), A[8]);
  float m3 = fmaxf(fmaxf(A[9], A[10]), A[11]);
  float m4 = fmaxf(fmaxf(A[12], A[13]), A[14]);
  return fmaxf(fmaxf(fmaxf(m0, m1), fmaxf(m2, m3)), m4);
}

__device__ __forceinline__ float dot15(const float* a, const float* b) {
  float d0 = a[0] * b[0], d1 = a[1] * b[1], d2 = a[2] * b[2];
  d0 = fmaf(a[3], b[3], d0);  d1 = fmaf(a[4], b[4], d1);  d2 = fmaf(a[5], b[5], d2);
  d0 = fmaf(a[6], b[6], d0);  d1 = fmaf(a[7], b[7], d1);  d2 = fmaf(a[8], b[8], d2);
  d0 = fmaf(a[9], b[9], d0);  d1 = fmaf(a[10], b[10], d1); d2 = fmaf(a[11], b[11], d2);
  d0 = fmaf(a[12], b[12], d0); d1 = fmaf(a[13], b[13], d1); d2 = fmaf(a[14], b[14], d2);
  return (d0 + d1) + d2;
}

// Wave-internal LDS broadcast read: 16 lanes of a group read the group's 16-float
// slot. Same-wave ds_write -> ds_read is ordered by the in-order LDS pipe; the
// asm memory clobber stops the compiler from caching/reordering LDS values.
__device__ __forceinline__ void bcast_read(const float4* slot4, float* E) {
  asm volatile("" ::: "memory");
  float4 u0 = slot4[0], u1 = slot4[1], u2 = slot4[2], u3 = slot4[3];
  E[0] = u0.x; E[1] = u0.y; E[2]  = u0.z; E[3]  = u0.w;
  E[4] = u1.x; E[5] = u1.y; E[6]  = u1.z; E[7]  = u1.w;
  E[8] = u2.x; E[9] = u2.y; E[10] = u2.z; E[11] = u2.w;
  E[12] = u3.x; E[13] = u3.y; E[14] = u3.z;
}

__global__ __launch_bounds__(256, 2)
void crf_fwdbwd(const float* __restrict__ logits, const int* __restrict__ yg,
                const float* __restrict__ trans, float* __restrict__ out)
{
  __shared__ float Tl[256];          // transitions, zero-padded (max idx 15*15+15=240)
  __shared__ int   yl[SPB * SEQ_T];  // staged labels for this block's 8 sequences
  __shared__ float bc[16][16];       // per-group broadcast slots
  __shared__ float comb[SPB][32];    // [0..14] alpha2_255, [15..29] beta2_256, [30] pathf, [31] pathb
  __shared__ float blks[SPB];

  const int tid = threadIdx.x;

  Tl[tid] = (tid < NTAGS * NTAGS) ? trans[tid] : 0.0f;
  {
    const int4* src = (const int4*)(yg + (size_t)blockIdx.x * (SPB * SEQ_T));
    int4* dst = (int4*)yl;
    #pragma unroll
    for (int k = 0; k < (SPB * SEQ_T / 4) / 256; ++k)   // 4 iterations
      dst[tid + k * 256] = src[tid + k * 256];
  }
  __syncthreads();

  const int wave = tid >> 6;
  const int lane = tid & 63;
  const int j  = lane & 15;                 // tag lane within group
  const int jj = (j < 15) ? j : 14;         // clamped (lane 15 is inert)
  const int sLoc = (wave >> 1) * 4 + (lane >> 4);   // 0..7: sequence within block
  const bool isFwd = (wave & 1) == 0;
  const int seq = blockIdx.x * SPB + sLoc;
  float* slot = &bc[tid >> 4][0];
  const float4* slot4 = (const float4*)slot;
  const int* ys = &yl[sLoc * SEQ_T];
  const float* ebase = logits + (size_t)seq * (SEQ_T * NTAGS) + jj;

  float W[15];
  float pacc = 0.0f;

  if (isFwd) {
    // lane j holds W column j: W[i] = e^{T[i][j]}
    #pragma unroll
    for (int i = 0; i < 15; ++i) W[i] = exp2f(Tl[i * 15 + jj] * LOG2E);

    // t = 0: alpha0 = logits[:,0,:]
    float a0 = ebase[0];
    int yp = ys[0];
    pacc = (j == yp && yp != PAD) ? a0 : 0.0f;
    slot[j] = a0 * LOG2E;
    float A[15];
    bcast_read(slot4, A);
    float M = max15(A);
    float E[15];
    #pragma unroll
    for (int i = 0; i < 15; ++i) E[i] = exp2f(A[i] - M);
    float Eown = E[jj];

    float buf[8];
    #pragma unroll
    for (int k = 0; k < 8; ++k) buf[k] = ebase[(1 + k) * 15];

    for (int tb = 1; tb <= 241; tb += 8) {
      #pragma unroll
      for (int k = 0; k < 8; ++k) {
        const int t = tb + k;
        float emit = buf[k];
        int tn = t + 8; tn = (tn > 255) ? 255 : tn;
        buf[k] = ebase[tn * 15];               // prefetch 8 steps ahead
        int yc = ys[t];
        float p = exp2f(emit * LOG2E);
        float dot = dot15(E, W);
        float newE = dot * p;
        bool mk = (yc != PAD);
        float own = mk ? newE : Eown;
        float tv = Tl[yp * 15 + yc];
        float add = emit + ((yp != PAD) ? tv : 0.0f);
        pacc += (mk && (j == yc)) ? add : 0.0f;
        slot[j] = own;
        bcast_read(slot4, E);
        Eown = own;
        yp = yc;
        if (k == 7) {                          // renorm every 8 steps
          float m = max15(E);
          float rs = 1.0f / m;
          #pragma unroll
          for (int i = 0; i < 15; ++i) E[i] *= rs;
          Eown *= rs;
          M += log2f(m);
        }
      }
    }
    // tail t = 249..255 (emit already in buf[0..6])
    #pragma unroll
    for (int k = 0; k < 7; ++k) {
      const int t = 249 + k;
      float emit = buf[k];
      int yc = ys[t];
      float p = exp2f(emit * LOG2E);
      float dot = dot15(E, W);
      float newE = dot * p;
      bool mk = (yc != PAD);
      float own = mk ? newE : Eown;
      float tv = Tl[yp * 15 + yc];
      float add = emit + ((yp != PAD) ? tv : 0.0f);
      pacc += (mk && (j == yc)) ? add : 0.0f;
      slot[j] = own;
      bcast_read(slot4, E);
      Eown = own;
      yp = yc;
    }
    #pragma unroll
    for (int k = 1; k < 16; k <<= 1) pacc += __shfl_xor(pacc, k, 16);
    if (j < 15) comb[sLoc][j] = M + log2f(Eown);
    if (j == 0) comb[sLoc][30] = pacc;
  } else {
    // backward: lane i holds W row i: W[k] = e^{T[i][k]}
    #pragma unroll
    for (int i = 0; i < 15; ++i) W[i] = exp2f(Tl[jj * 15 + i] * LOG2E);

    float Eb = 1.0f, Mb = 0.0f;     // beta_{512} = 0  ->  E=1, M=0
    int yc = ys[511];
    float buf[8];
    #pragma unroll
    for (int k = 0; k < 8; ++k) buf[k] = ebase[(511 - k) * 15];

    float Q[15];
    for (int tb = 511; tb >= 271; tb -= 8) {
      #pragma unroll
      for (int k = 0; k < 8; ++k) {
        const int t = tb - k;
        float emit = buf[k];
        int tn = t - 8; tn = (tn < 256) ? 256 : tn;
        buf[k] = ebase[tn * 15];
        int yp2 = ys[t - 1];
        float p = exp2f(emit * LOG2E);
        float q = Eb * p;
        slot[j] = q;
        bcast_read(slot4, Q);
        float dot = dot15(W, Q);
        bool mk = (yc != PAD);
        Eb = mk ? dot : Eb;
        float tv = Tl[yp2 * 15 + yc];
        float add = emit + ((yp2 != PAD) ? tv : 0.0f);
        pacc += (mk && (j == yc)) ? add : 0.0f;
        yc = yp2;
        if (k == 7) {
          float m = max15(Q);
          float rs = 1.0f / m;
          Eb *= rs;
          Mb += log2f(m);
        }
      }
    }
    // tail t = 263..256 (emit in buf[0..7])
    #pragma unroll
    for (int k = 0; k < 8; ++k) {
      const int t = 263 - k;
      float emit = buf[k];
      int yp2 = ys[t - 1];
      float p = exp2f(emit * LOG2E);
      float q = Eb * p;
      slot[j] = q;
      bcast_read(slot4, Q);
      float dot = dot15(W, Q);
      bool mk = (yc != PAD);
      Eb = mk ? dot : Eb;
      float tv = Tl[yp2 * 15 + yc];
      float add = emit + ((yp2 != PAD) ? tv : 0.0f);
      pacc += (mk && (j == yc)) ? add : 0.0f;
      yc = yp2;
    }
    #pragma unroll
    for (int k = 1; k < 16; k <<= 1) pacc += __shfl_xor(pacc, k, 16);
    if (j < 15) comb[sLoc][15 + j] = Mb + log2f(Eb);
    if (j == 0) comb[sLoc][31] = pacc;
  }

  __syncthreads();

  if (tid < SPB) {
    const float* c = comb[tid];
    float s[15];
    #pragma unroll
    for (int i = 0; i < 15; ++i) s[i] = c[i] + c[15 + i];
    float m = max15(s);
    float sum = 0.0f;
    #pragma unroll
    for (int i = 0; i < 15; ++i) sum += exp2f(s[i] - m);
    float logZ = (m + log2f(sum)) * LN2;
    float path = c[30] + c[31];
    float nll = logZ - path;
    nll = fminf(fmaxf(nll, 0.0f), 1000000.0f);
    blks[tid] = nll;
  }
  __syncthreads();
  if (tid == 0) {
    float tot = 0.0f;
    #pragma unroll
    for (int i = 0; i < SPB; ++i) tot += blks[i];
    atomicAdd(out, tot * (1.0f / 4096.0f));
  }
}

extern "C" void kernel_launch(void* const* d_in, const int* in_sizes, int n_in,
                              void* d_out, int out_size, void* d_ws, size_t ws_size,
                              hipStream_t stream) {
  const float* logits = (const float*)d_in[0];   // (4096, 512, 15) f32
  const int*   y      = (const int*)d_in[1];     // (4096, 512) i32
  const float* trans  = (const float*)d_in[2];   // (15, 15) f32
  float* out = (float*)d_out;

  hipMemsetAsync(out, 0, sizeof(float), stream);

  const int B = in_sizes[1] / SEQ_T;             // 4096
  const int blocks = B / SPB;                    // 512
  crf_fwdbwd<<<dim3(blocks), dim3(256), 0, stream>>>(logits, y, trans, out);
}